// Round 1
// baseline (40526.102 us; speedup 1.0000x reference)
//
#include <hip/hip_runtime.h>
#include <math.h>

#define B_SZ 128
#define T_SZ 128
#define EMBD 300
#define ND 512
#define G3 1536

__device__ __forceinline__ float sigmoidf_(float x) { return 1.0f / (1.0f + expf(-x)); }

// C[M,N] = (gather(A) @ B^T) + bias + addC
// A rows gathered via idxA if non-null. B is (N,K) row-major (ldB).
// Block tile: (TM*16) x 64, 256 threads, each thread TM x 4.
template<int TM>
__global__ void gemm_nt(const float* __restrict__ A, const int* __restrict__ idxA,
                        const float* __restrict__ Bm, const float* __restrict__ bias,
                        const float* __restrict__ addC, float* __restrict__ C,
                        int M, int N, int K, int ldA, int ldB, int ldC)
{
    __shared__ float As[16][TM * 16 + 1];
    __shared__ float Bs[16][64 + 1];
    const int tid = threadIdx.x;
    const int tx = tid & 15;   // n group
    const int ty = tid >> 4;   // m group
    const int m0 = blockIdx.y * (TM * 16);
    const int n0 = blockIdx.x * 64;

    float acc[TM][4];
#pragma unroll
    for (int i = 0; i < TM; ++i)
#pragma unroll
        for (int j = 0; j < 4; ++j) acc[i][j] = 0.0f;

    for (int k0 = 0; k0 < K; k0 += 16) {
        // load A tile (TM*16 rows x 16 k), TM elems per thread
#pragma unroll
        for (int i = 0; i < TM; ++i) {
            int m = (tid >> 4) + i * 16;
            int k = tid & 15;
            int gm = m0 + m, gk = k0 + k;
            float v = 0.0f;
            if (gm < M && gk < K) {
                long row = idxA ? (long)idxA[gm] : (long)gm;
                v = A[row * (long)ldA + gk];
            }
            As[k][m] = v;
        }
        // load B tile (64 x 16), 4 per thread
#pragma unroll
        for (int i = 0; i < 4; ++i) {
            int n = (tid >> 4) + i * 16;
            int k = tid & 15;
            int gn = n0 + n, gk = k0 + k;
            float v = 0.0f;
            if (gn < N && gk < K) v = Bm[(long)gn * ldB + gk];
            Bs[k][n] = v;
        }
        __syncthreads();
#pragma unroll
        for (int kk = 0; kk < 16; ++kk) {
            float bv[4];
#pragma unroll
            for (int j = 0; j < 4; ++j) bv[j] = Bs[kk][tx * 4 + j];
#pragma unroll
            for (int i = 0; i < TM; ++i) {
                float av = As[kk][ty * TM + i];
#pragma unroll
                for (int j = 0; j < 4; ++j) acc[i][j] += av * bv[j];
            }
        }
        __syncthreads();
    }
#pragma unroll
    for (int i = 0; i < TM; ++i) {
        int gm = m0 + ty * TM + i;
        if (gm >= M) continue;
#pragma unroll
        for (int j = 0; j < 4; ++j) {
            int gn = n0 + tx * 4 + j;
            if (gn >= N) continue;
            float v = acc[i][j];
            if (bias) v += bias[gn];
            if (addC) v += addC[(long)gm * ldC + gn];
            C[(long)gm * ldC + gn] = v;
        }
    }
}

__global__ void prep_idx(const int* __restrict__ prem, const int* __restrict__ hyp,
                         int* __restrict__ idx_p, int* __restrict__ idx_h)
{
    int i = blockIdx.x * blockDim.x + threadIdx.x;
    if (i < B_SZ * T_SZ) {
        int t = i / B_SZ, b = i % B_SZ;
        idx_p[i] = prem[b * T_SZ + t];
        idx_h[i] = hyp[b * T_SZ + t];
    }
}

__global__ void transpose_sq(const float* __restrict__ in, float* __restrict__ out, int n)
{
    int i = blockIdx.x * blockDim.x + threadIdx.x;
    if (i < n * n) { int r = i / n, c = i % n; out[c * n + r] = in[i]; }
}

__global__ void zero_kernel(float* __restrict__ p, int n)
{
    int i = blockIdx.x * blockDim.x + threadIdx.x;
    if (i < n) p[i] = 0.0f;
}

// GRU gate combine + masking. gi/gh are (B, 3*ND) with [r|z|n] layout.
// h updated in place: h = hr*m + h*(1-m).
// If o_out != null: o_out = first ? hr : hr*m + o_prev*(1-m).
__global__ void gru_combine(const float* __restrict__ gi, const float* __restrict__ gh,
                            float* __restrict__ h, const float* __restrict__ o_prev,
                            float* __restrict__ o_out, const int* __restrict__ toks,
                            int t, int first)
{
    int i = blockIdx.x * blockDim.x + threadIdx.x;
    if (i >= B_SZ * ND) return;
    int b = i / ND, d = i % ND;
    const float* gib = gi + (long)b * G3;
    const float* ghb = gh + (long)b * G3;
    float r = sigmoidf_(gib[d] + ghb[d]);
    float z = sigmoidf_(gib[ND + d] + ghb[ND + d]);
    float n = tanhf(gib[2 * ND + d] + r * ghb[2 * ND + d]);
    float hp = h[i];
    float hr = (1.0f - z) * n + z * hp;
    float m = (toks[b * T_SZ + t] != 0) ? 1.0f : 0.0f;
    h[i] = hr * m + hp * (1.0f - m);
    if (o_out) o_out[i] = first ? hr : (hr * m + o_prev[i] * (1.0f - m));
}

// alpha logit for (b, t'): sum_n tanh(Yw[t'*B+b][n] + s[b][n]) * Walpha[n], masked.
// One 64-lane wave per (b,t').
__global__ void alpha_logits(const float* __restrict__ Yw, const float* __restrict__ s,
                             const float* __restrict__ Walpha, const int* __restrict__ prem,
                             float* __restrict__ alphaBuf)
{
    int wid = (blockIdx.x * blockDim.x + threadIdx.x) >> 6;
    int lane = threadIdx.x & 63;
    if (wid >= B_SZ * T_SZ) return;
    int tp = wid / B_SZ, b = wid % B_SZ;
    const float* yw = Yw + (long)wid * ND;
    const float* sb = s + (long)b * ND;
    float acc = 0.0f;
    for (int k = lane; k < ND; k += 64)
        acc += tanhf(yw[k] + sb[k]) * Walpha[k];
#pragma unroll
    for (int off = 32; off; off >>= 1) acc += __shfl_down(acc, off);
    if (lane == 0) {
        float m = (prem[b * T_SZ + tp] != 0) ? 1.0f : 0.0f;
        alphaBuf[b * T_SZ + tp] = acc - 1000.0f * (1.0f - m);
    }
}

// softmax over t' (128) per b, then a[b][:] = sum_t alpha[t] * Y[t*B+b][:]
__global__ void attn_apply(const float* __restrict__ alphaBuf, const float* __restrict__ Y,
                           float* __restrict__ a)
{
    __shared__ float sh[T_SZ];
    __shared__ float red[2];
    int b = blockIdx.x;
    int tid = threadIdx.x;
    if (tid < T_SZ) sh[tid] = alphaBuf[b * T_SZ + tid];
    __syncthreads();
    if (tid < 64) {
        float v = fmaxf(sh[tid], sh[tid + 64]);
#pragma unroll
        for (int off = 32; off; off >>= 1) v = fmaxf(v, __shfl_down(v, off));
        if (tid == 0) red[0] = v;
    }
    __syncthreads();
    float mx = red[0];
    if (tid < T_SZ) sh[tid] = expf(sh[tid] - mx);
    __syncthreads();
    if (tid < 64) {
        float v = sh[tid] + sh[tid + 64];
#pragma unroll
        for (int off = 32; off; off >>= 1) v += __shfl_down(v, off);
        if (tid == 0) red[1] = v;
    }
    __syncthreads();
    float inv = 1.0f / red[1];
    float acc0 = 0.0f, acc1 = 0.0f;
    for (int t = 0; t < T_SZ; ++t) {
        float al = sh[t] * inv;
        const float* y = Y + ((long)t * B_SZ + b) * ND;
        acc0 += al * y[tid];
        acc1 += al * y[tid + 256];
    }
    a[b * ND + tid] = acc0;
    a[b * ND + tid + 256] = acc1;
}

// logits = r @ outW^T + outb; log_softmax over 3. One 64-lane block per b.
__global__ void final_logits(const float* __restrict__ r, const float* __restrict__ outW,
                             const float* __restrict__ outb, float* __restrict__ out)
{
    int b = blockIdx.x;
    int lane = threadIdx.x;
    float a0 = 0.0f, a1 = 0.0f, a2 = 0.0f;
    for (int k = lane; k < ND; k += 64) {
        float rv = r[b * ND + k];
        a0 += rv * outW[0 * ND + k];
        a1 += rv * outW[1 * ND + k];
        a2 += rv * outW[2 * ND + k];
    }
#pragma unroll
    for (int off = 32; off; off >>= 1) {
        a0 += __shfl_down(a0, off);
        a1 += __shfl_down(a1, off);
        a2 += __shfl_down(a2, off);
    }
    if (lane == 0) {
        float l0 = a0 + outb[0], l1 = a1 + outb[1], l2 = a2 + outb[2];
        float mx = fmaxf(l0, fmaxf(l1, l2));
        float se = expf(l0 - mx) + expf(l1 - mx) + expf(l2 - mx);
        float ls = mx + logf(se);
        out[b * 3 + 0] = l0 - ls;
        out[b * 3 + 1] = l1 - ls;
        out[b * 3 + 2] = l2 - ls;
    }
}

extern "C" void kernel_launch(void* const* d_in, const int* in_sizes, int n_in,
                              void* d_out, int out_size, void* d_ws, size_t ws_size,
                              hipStream_t stream)
{
    const int*   prem    = (const int*)d_in[0];
    const int*   hyp     = (const int*)d_in[1];
    const float* E       = (const float*)d_in[2];
    const float* p_Wih   = (const float*)d_in[3];
    const float* p_Whh   = (const float*)d_in[4];
    const float* p_bih   = (const float*)d_in[5];
    const float* p_bhh   = (const float*)d_in[6];
    const float* h_Wih   = (const float*)d_in[7];
    const float* h_Whh   = (const float*)d_in[8];
    const float* h_bih   = (const float*)d_in[9];
    const float* h_bhh   = (const float*)d_in[10];
    const float* m_Wih   = (const float*)d_in[11];
    const float* m_Whh   = (const float*)d_in[12];
    const float* m_bih   = (const float*)d_in[13];
    const float* m_bhh   = (const float*)d_in[14];
    const float* W_y     = (const float*)d_in[15];
    const float* W_h     = (const float*)d_in[16];
    const float* W_r     = (const float*)d_in[17];
    const float* W_alpha = (const float*)d_in[18];
    const float* out_W   = (const float*)d_in[19];
    const float* out_b   = (const float*)d_in[20];
    float* out = (float*)d_out;

    float* ws = (float*)d_ws;
    size_t off = 0;
    float* GI   = ws + off; off += (size_t)T_SZ * B_SZ * G3;   // 25165824 (reused 3x)
    float* o_p  = ws + off; off += (size_t)T_SZ * B_SZ * ND;   // premise outputs Y
    float* o_h  = ws + off; off += (size_t)T_SZ * B_SZ * ND;
    float* Yw   = ws + off; off += (size_t)T_SZ * B_SZ * ND;
    float* OHWh = ws + off; off += (size_t)T_SZ * B_SZ * ND;
    float* WyT  = ws + off; off += (size_t)ND * ND;
    float* WhT  = ws + off; off += (size_t)ND * ND;
    float* WrT  = ws + off; off += (size_t)ND * ND;
    float* h    = ws + off; off += (size_t)B_SZ * ND;
    float* r_   = ws + off; off += (size_t)B_SZ * ND;
    float* ghb  = ws + off; off += (size_t)B_SZ * G3;
    float* gib  = ws + off; off += (size_t)B_SZ * G3;
    float* sbuf = ws + off; off += (size_t)B_SZ * ND;
    float* abuf = ws + off; off += (size_t)B_SZ * ND;
    float* alphaBuf = ws + off; off += (size_t)B_SZ * T_SZ;
    int* idx_p = (int*)(ws + off); off += (size_t)B_SZ * T_SZ;
    int* idx_h = (int*)(ws + off); off += (size_t)B_SZ * T_SZ;
    if (ws_size < off * sizeof(float)) return;  // workspace too small -> bench will flag

    auto gemm4 = [&](const float* A, const int* idxA, const float* Bm, const float* bias,
                     const float* addC, float* C, int M, int N, int K, int ldA, int ldB, int ldC) {
        dim3 g((N + 63) / 64, (M + 63) / 64);
        gemm_nt<4><<<g, 256, 0, stream>>>(A, idxA, Bm, bias, addC, C, M, N, K, ldA, ldB, ldC);
    };
    auto gemm2 = [&](const float* A, const int* idxA, const float* Bm, const float* bias,
                     const float* addC, float* C, int M, int N, int K, int ldA, int ldB, int ldC) {
        dim3 g((N + 63) / 64, (M + 31) / 32);
        gemm_nt<2><<<g, 256, 0, stream>>>(A, idxA, Bm, bias, addC, C, M, N, K, ldA, ldB, ldC);
    };

    // ---- prep ----
    prep_idx<<<(B_SZ * T_SZ + 255) / 256, 256, 0, stream>>>(prem, hyp, idx_p, idx_h);
    transpose_sq<<<(ND * ND + 255) / 256, 256, 0, stream>>>(W_y, WyT, ND);
    transpose_sq<<<(ND * ND + 255) / 256, 256, 0, stream>>>(W_h, WhT, ND);
    transpose_sq<<<(ND * ND + 255) / 256, 256, 0, stream>>>(W_r, WrT, ND);
    zero_kernel<<<(B_SZ * ND + 255) / 256, 256, 0, stream>>>(h, B_SZ * ND);

    const int MB = T_SZ * B_SZ;  // 16384

    // ---- premise GRU ----
    gemm4(E, idx_p, p_Wih, p_bih, nullptr, GI, MB, G3, EMBD, EMBD, EMBD, G3);
    for (int t = 0; t < T_SZ; ++t) {
        gemm2(h, nullptr, p_Whh, p_bhh, nullptr, ghb, B_SZ, G3, ND, ND, ND, G3);
        const float* oprev = (t == 0) ? o_p : o_p + (size_t)(t - 1) * B_SZ * ND;
        gru_combine<<<(B_SZ * ND + 255) / 256, 256, 0, stream>>>(
            GI + (size_t)t * B_SZ * G3, ghb, h, oprev, o_p + (size_t)t * B_SZ * ND,
            prem, t, t == 0 ? 1 : 0);
    }

    // ---- hypothesis GRU (h continues as h_n) ----
    gemm4(E, idx_h, h_Wih, h_bih, nullptr, GI, MB, G3, EMBD, EMBD, EMBD, G3);
    for (int t = 0; t < T_SZ; ++t) {
        gemm2(h, nullptr, h_Whh, h_bhh, nullptr, ghb, B_SZ, G3, ND, ND, ND, G3);
        const float* oprev = (t == 0) ? o_h : o_h + (size_t)(t - 1) * B_SZ * ND;
        gru_combine<<<(B_SZ * ND + 255) / 256, 256, 0, stream>>>(
            GI + (size_t)t * B_SZ * G3, ghb, h, oprev, o_h + (size_t)t * B_SZ * ND,
            hyp, t, t == 0 ? 1 : 0);
    }

    // ---- attention precompute ----
    gemm4(o_p, nullptr, WyT, nullptr, nullptr, Yw, MB, ND, ND, ND, ND, ND);
    gemm4(o_h, nullptr, WhT, nullptr, nullptr, OHWh, MB, ND, ND, ND, ND, ND);
    // OH_GI = o_h @ m_Wih[:,512:]^T + m_bih  (reuses GI buffer)
    gemm4(o_h, nullptr, m_Wih + ND, m_bih, nullptr, GI, MB, G3, ND, ND, 2 * ND, G3);
    zero_kernel<<<(B_SZ * ND + 255) / 256, 256, 0, stream>>>(r_, B_SZ * ND);

    // ---- match loop ----
    for (int t = 0; t < T_SZ; ++t) {
        // s = OHWh[t] + r @ W_r
        gemm2(r_, nullptr, WrT, nullptr, OHWh + (size_t)t * B_SZ * ND, sbuf,
              B_SZ, ND, ND, ND, ND, ND);
        alpha_logits<<<(B_SZ * T_SZ * 64) / 256, 256, 0, stream>>>(Yw, sbuf, W_alpha, prem, alphaBuf);
        attn_apply<<<B_SZ, 256, 0, stream>>>(alphaBuf, o_p, abuf);
        // gi = a @ m_Wih[:,:512]^T + OH_GI[t]   (OH_GI already has m_bih)
        gemm2(abuf, nullptr, m_Wih, nullptr, GI + (size_t)t * B_SZ * G3, gib,
              B_SZ, G3, ND, ND, 2 * ND, G3);
        // gh = r @ m_Whh^T + m_bhh
        gemm2(r_, nullptr, m_Whh, m_bhh, nullptr, ghb, B_SZ, G3, ND, ND, ND, G3);
        gru_combine<<<(B_SZ * ND + 255) / 256, 256, 0, stream>>>(
            gib, ghb, r_, nullptr, nullptr, hyp, t, 0);
    }

    final_logits<<<B_SZ, 64, 0, stream>>>(r_, out_W, out_b, out);
}

// Round 2
// 12824.089 us; speedup vs baseline: 3.1602x; 3.1602x over previous
//
#include <hip/hip_runtime.h>
#include <math.h>

#define B_SZ 128
#define T_SZ 128
#define EMBD 300
#define ND 512
#define G3 1536

typedef short s16x8 __attribute__((ext_vector_type(8)));
typedef float f32x4 __attribute__((ext_vector_type(4)));

__device__ __forceinline__ float sigmoidf_(float x) { return 1.0f / (1.0f + expf(-x)); }

__device__ __forceinline__ unsigned short f2b(float x) {
    unsigned u = __float_as_uint(x);
    unsigned r = (u + 0x7fff + ((u >> 16) & 1)) >> 16;  // RNE
    return (unsigned short)r;
}

// ---------------- MFMA GEMM ----------------
// C[M,N] = gather(A,idxA) @ Wb^T  (+bias) (+addC)
// A: fp32 (converted to bf16 in staging). Wb: bf16 (N x Kpad) row-major, zero-padded past K.
// Block: 256 thr = 4 waves (2x2), tile 64x64, BK=32, mfma 16x16x32 bf16.
__global__ __launch_bounds__(256)
void mfma_gemm(const float* __restrict__ A, const int* __restrict__ idxA,
               const unsigned short* __restrict__ Wb, const float* __restrict__ bias,
               const float* __restrict__ addC, float* __restrict__ C,
               int M, int N, int K, int ldA, int Kpad, int ldC, int ldAdd)
{
    __shared__ unsigned short As[64][40];   // pad 32->40: 2-way max on b128
    __shared__ unsigned short Bs[64][40];
    const int tid = threadIdx.x;
    const int wv = tid >> 6, lane = tid & 63;
    const int wm = wv >> 1, wn = wv & 1;
    const int m0 = blockIdx.y * 64, n0 = blockIdx.x * 64;

    f32x4 acc[2][2] = {{{0.f,0.f,0.f,0.f},{0.f,0.f,0.f,0.f}},
                       {{0.f,0.f,0.f,0.f},{0.f,0.f,0.f,0.f}}};

    const int r_st = tid >> 2;        // staging row 0..63
    const int k_st = (tid & 3) * 8;   // 0,8,16,24

    long arow = -1;
    {
        int gm = m0 + r_st;
        if (gm < M) arow = idxA ? (long)idxA[gm] : (long)gm;
    }

    const int kIters = (K + 31) / 32;
    for (int it = 0; it < kIters; ++it) {
        const int k0 = it * 32;
        // ---- stage A (fp32 -> bf16) ----
        {
            float v[8];
            const int kg = k0 + k_st;
            if (arow >= 0 && kg + 8 <= K) {
                const float* p = A + arow * (long)ldA + kg;
                f32x4 u0 = *(const f32x4*)p;
                f32x4 u1 = *(const f32x4*)(p + 4);
#pragma unroll
                for (int j = 0; j < 4; ++j) { v[j] = u0[j]; v[4 + j] = u1[j]; }
            } else {
#pragma unroll
                for (int j = 0; j < 8; ++j) {
                    int kk = kg + j;
                    v[j] = (arow >= 0 && kk < K) ? A[arow * (long)ldA + kk] : 0.0f;
                }
            }
            s16x8 pk;
#pragma unroll
            for (int j = 0; j < 8; ++j) pk[j] = (short)f2b(v[j]);
            *(s16x8*)&As[r_st][k_st] = pk;
        }
        // ---- stage B (bf16 direct) ----
        {
            int gn = n0 + r_st;
            s16x8 pk = {0,0,0,0,0,0,0,0};
            if (gn < N) pk = *(const s16x8*)&Wb[(long)gn * Kpad + k0 + k_st];
            *(s16x8*)&Bs[r_st][k_st] = pk;
        }
        __syncthreads();
        // ---- fragments + mfma ----
        {
            const int koff = (lane >> 4) * 8;
            s16x8 af[2], bfr[2];
#pragma unroll
            for (int f = 0; f < 2; ++f) {
                af[f]  = *(s16x8*)&As[wm * 32 + f * 16 + (lane & 15)][koff];
                bfr[f] = *(s16x8*)&Bs[wn * 32 + f * 16 + (lane & 15)][koff];
            }
#pragma unroll
            for (int fi = 0; fi < 2; ++fi)
#pragma unroll
                for (int fj = 0; fj < 2; ++fj)
                    acc[fi][fj] = __builtin_amdgcn_mfma_f32_16x16x32_bf16(
                        af[fi], bfr[fj], acc[fi][fj], 0, 0, 0);
        }
        __syncthreads();
    }
    // ---- epilogue: C/D layout col=lane&15, row=(lane>>4)*4+r ----
#pragma unroll
    for (int fi = 0; fi < 2; ++fi)
#pragma unroll
        for (int fj = 0; fj < 2; ++fj)
#pragma unroll
            for (int r = 0; r < 4; ++r) {
                int m = m0 + wm * 32 + fi * 16 + (lane >> 4) * 4 + r;
                int n = n0 + wn * 32 + fj * 16 + (lane & 15);
                if (m < M && n < N) {
                    float v = acc[fi][fj][r];
                    if (bias) v += bias[n];
                    if (addC) v += addC[(long)m * ldAdd + n];
                    C[(long)m * ldC + n] = v;
                }
            }
}

// ---------------- prep kernels ----------------
__global__ void prep_idx(const int* __restrict__ prem, const int* __restrict__ hyp,
                         int* __restrict__ idx_p, int* __restrict__ idx_h)
{
    int i = blockIdx.x * blockDim.x + threadIdx.x;
    if (i < B_SZ * T_SZ) {
        int t = i / B_SZ, b = i % B_SZ;
        idx_p[i] = prem[b * T_SZ + t];
        idx_h[i] = hyp[b * T_SZ + t];
    }
}

// out[n*Kpad+k] = bf16(in[n*ldIn + k + colOff]) for k<K else 0
__global__ void conv_w(const float* __restrict__ in, unsigned short* __restrict__ out,
                       int N, int K, int Kpad, int ldIn, int colOff)
{
    int i = blockIdx.x * blockDim.x + threadIdx.x;
    if (i >= N * Kpad) return;
    int n = i / Kpad, k = i % Kpad;
    float v = (k < K) ? in[(long)n * ldIn + k + colOff] : 0.0f;
    out[i] = f2b(v);
}

// out[n*Kpad+k] = bf16(in[k*ldIn + n]) for k<K else 0 (transpose)
__global__ void conv_wT(const float* __restrict__ in, unsigned short* __restrict__ out,
                        int N, int K, int Kpad, int ldIn)
{
    int i = blockIdx.x * blockDim.x + threadIdx.x;
    if (i >= N * Kpad) return;
    int n = i / Kpad, k = i % Kpad;
    float v = (k < K) ? in[(long)k * ldIn + n] : 0.0f;
    out[i] = f2b(v);
}

__global__ void make_bias_cat(const float* __restrict__ m_bhh, float* __restrict__ out)
{
    int i = blockIdx.x * blockDim.x + threadIdx.x;
    if (i < 2048) out[i] = (i < ND) ? 0.0f : m_bhh[i - ND];
}

__global__ void zero_kernel(float* __restrict__ p, int n)
{
    int i = blockIdx.x * blockDim.x + threadIdx.x;
    if (i < n) p[i] = 0.0f;
}

// ---------------- GRU combine ----------------
// gates at gi[b*ldGI + g*ND + d], gh[b*ldGH + g*ND + d]
__global__ void gru_combine(const float* __restrict__ gi, int ldGI,
                            const float* __restrict__ gh, int ldGH,
                            float* __restrict__ h, const float* __restrict__ o_prev,
                            float* __restrict__ o_out, const int* __restrict__ toks,
                            int t, int first)
{
    int i = blockIdx.x * blockDim.x + threadIdx.x;
    if (i >= B_SZ * ND) return;
    int b = i / ND, d = i % ND;
    const float* gib = gi + (long)b * ldGI;
    const float* ghb = gh + (long)b * ldGH;
    float r = sigmoidf_(gib[d] + ghb[d]);
    float z = sigmoidf_(gib[ND + d] + ghb[ND + d]);
    float n = tanhf(gib[2 * ND + d] + r * ghb[2 * ND + d]);
    float hp = h[i];
    float hr = (1.0f - z) * n + z * hp;
    float m = (toks[b * T_SZ + t] != 0) ? 1.0f : 0.0f;
    h[i] = hr * m + hp * (1.0f - m);
    if (o_out) o_out[i] = first ? hr : (hr * m + o_prev[i] * (1.0f - m));
}

// ---------------- attention kernels ----------------
// alpha logit (b,t'): Walpha . tanh(Yw[t'*B+b] + s[b] + oh[b]); one 64-lane wave each
__global__ void alpha_logits(const float* __restrict__ Yw, const float* __restrict__ scat,
                             int lds, const float* __restrict__ oh,
                             const float* __restrict__ Walpha, const int* __restrict__ prem,
                             float* __restrict__ alphaBuf)
{
    int wid = (blockIdx.x * blockDim.x + threadIdx.x) >> 6;
    int lane = threadIdx.x & 63;
    if (wid >= B_SZ * T_SZ) return;
    int tp = wid / B_SZ, b = wid % B_SZ;
    const float* yw = Yw + (long)wid * ND;
    const float* sb = scat + (long)b * lds;
    const float* ob = oh + (long)b * ND;
    float acc = 0.0f;
    for (int k = lane; k < ND; k += 64)
        acc += tanhf(yw[k] + sb[k] + ob[k]) * Walpha[k];
#pragma unroll
    for (int off = 32; off; off >>= 1) acc += __shfl_down(acc, off);
    if (lane == 0) {
        float m = (prem[b * T_SZ + tp] != 0) ? 1.0f : 0.0f;
        alphaBuf[b * T_SZ + tp] = acc - 1000.0f * (1.0f - m);
    }
}

// softmax over t' then a[b] = sum_t alpha[t] * Y[t*B+b]
__global__ void attn_apply(const float* __restrict__ alphaBuf, const float* __restrict__ Y,
                           float* __restrict__ a)
{
    __shared__ float sh[T_SZ];
    __shared__ float red[2];
    int b = blockIdx.x;
    int tid = threadIdx.x;
    if (tid < T_SZ) sh[tid] = alphaBuf[b * T_SZ + tid];
    __syncthreads();
    if (tid < 64) {
        float v = fmaxf(sh[tid], sh[tid + 64]);
#pragma unroll
        for (int off = 32; off; off >>= 1) v = fmaxf(v, __shfl_down(v, off));
        if (tid == 0) red[0] = v;
    }
    __syncthreads();
    float mx = red[0];
    if (tid < T_SZ) sh[tid] = expf(sh[tid] - mx);
    __syncthreads();
    if (tid < 64) {
        float v = sh[tid] + sh[tid + 64];
#pragma unroll
        for (int off = 32; off; off >>= 1) v += __shfl_down(v, off);
        if (tid == 0) red[1] = v;
    }
    __syncthreads();
    float inv = 1.0f / red[1];
    float acc0 = 0.0f, acc1 = 0.0f;
    for (int t = 0; t < T_SZ; ++t) {
        float al = sh[t] * inv;
        const float* y = Y + ((long)t * B_SZ + b) * ND;
        acc0 += al * y[tid];
        acc1 += al * y[tid + 256];
    }
    a[b * ND + tid] = acc0;
    a[b * ND + tid + 256] = acc1;
}

__global__ void final_logits(const float* __restrict__ r, const float* __restrict__ outW,
                             const float* __restrict__ outb, float* __restrict__ out)
{
    int b = blockIdx.x;
    int lane = threadIdx.x;
    float a0 = 0.0f, a1 = 0.0f, a2 = 0.0f;
    for (int k = lane; k < ND; k += 64) {
        float rv = r[b * ND + k];
        a0 += rv * outW[0 * ND + k];
        a1 += rv * outW[1 * ND + k];
        a2 += rv * outW[2 * ND + k];
    }
#pragma unroll
    for (int off = 32; off; off >>= 1) {
        a0 += __shfl_down(a0, off);
        a1 += __shfl_down(a1, off);
        a2 += __shfl_down(a2, off);
    }
    if (lane == 0) {
        float l0 = a0 + outb[0], l1 = a1 + outb[1], l2 = a2 + outb[2];
        float mx = fmaxf(l0, fmaxf(l1, l2));
        float se = expf(l0 - mx) + expf(l1 - mx) + expf(l2 - mx);
        float ls = mx + logf(se);
        out[b * 3 + 0] = l0 - ls;
        out[b * 3 + 1] = l1 - ls;
        out[b * 3 + 2] = l2 - ls;
    }
}

// ---------------- host ----------------
extern "C" void kernel_launch(void* const* d_in, const int* in_sizes, int n_in,
                              void* d_out, int out_size, void* d_ws, size_t ws_size,
                              hipStream_t stream)
{
    const int*   prem    = (const int*)d_in[0];
    const int*   hyp     = (const int*)d_in[1];
    const float* E       = (const float*)d_in[2];
    const float* p_Wih   = (const float*)d_in[3];
    const float* p_Whh   = (const float*)d_in[4];
    const float* p_bih   = (const float*)d_in[5];
    const float* p_bhh   = (const float*)d_in[6];
    const float* h_Wih   = (const float*)d_in[7];
    const float* h_Whh   = (const float*)d_in[8];
    const float* h_bih   = (const float*)d_in[9];
    const float* h_bhh   = (const float*)d_in[10];
    const float* m_Wih   = (const float*)d_in[11];
    const float* m_Whh   = (const float*)d_in[12];
    const float* m_bih   = (const float*)d_in[13];
    const float* m_bhh   = (const float*)d_in[14];
    const float* W_y     = (const float*)d_in[15];
    const float* W_h     = (const float*)d_in[16];
    const float* W_r     = (const float*)d_in[17];
    const float* W_alpha = (const float*)d_in[18];
    const float* out_W   = (const float*)d_in[19];
    const float* out_b   = (const float*)d_in[20];
    float* out = (float*)d_out;

    const int MB = T_SZ * B_SZ;  // 16384

    float* ws = (float*)d_ws;
    size_t off = 0;
    float* GI   = ws + off; off += (size_t)MB * G3;        // premise GI / hyp GI / OH_GI
    float* o_p  = ws + off; off += (size_t)MB * ND;        // Y
    float* o_h  = ws + off; off += (size_t)MB * ND;
    float* Yw   = ws + off; off += (size_t)MB * ND;
    float* OHWh = ws + off; off += (size_t)MB * ND;
    float* h    = ws + off; off += (size_t)B_SZ * ND;
    float* r_   = ws + off; off += (size_t)B_SZ * ND;
    float* ghb  = ws + off; off += (size_t)B_SZ * G3;
    float* gib  = ws + off; off += (size_t)B_SZ * G3;
    float* scat = ws + off; off += (size_t)B_SZ * 2048;    // [s | gh] merged
    float* abuf = ws + off; off += (size_t)B_SZ * ND;
    float* alphaBuf = ws + off; off += (size_t)B_SZ * T_SZ;
    float* bias_cat = ws + off; off += 2048;
    int* idx_p = (int*)(ws + off); off += (size_t)B_SZ * T_SZ;
    int* idx_h = (int*)(ws + off); off += (size_t)B_SZ * T_SZ;
    // bf16 weights (ushort), sizes in float units = count/2 (counts all even)
    unsigned short* wsh = (unsigned short*)(ws + off);
    size_t uoff = 0;
    unsigned short* pWih_b = wsh + uoff; uoff += (size_t)G3 * 320;
    unsigned short* hWih_b = wsh + uoff; uoff += (size_t)G3 * 320;
    unsigned short* pWhh_b = wsh + uoff; uoff += (size_t)G3 * ND;
    unsigned short* hWhh_b = wsh + uoff; uoff += (size_t)G3 * ND;
    unsigned short* mWihL  = wsh + uoff; uoff += (size_t)G3 * ND;
    unsigned short* mWihR  = wsh + uoff; uoff += (size_t)G3 * ND;
    unsigned short* WyT_b  = wsh + uoff; uoff += (size_t)ND * ND;
    unsigned short* WhT_b  = wsh + uoff; uoff += (size_t)ND * ND;
    unsigned short* Wcat   = wsh + uoff; uoff += (size_t)2048 * ND;  // [W_r^T ; m_Whh]
    off += uoff / 2;
    if (ws_size < off * sizeof(float)) return;

    auto gemm = [&](const float* A, const int* idxA, const unsigned short* Wb,
                    const float* bias, const float* addC, float* C,
                    int M, int N, int K, int ldA, int Kpad, int ldC, int ldAdd) {
        dim3 g(N / 64, (M + 63) / 64);
        mfma_gemm<<<g, 256, 0, stream>>>(A, idxA, Wb, bias, addC, C, M, N, K, ldA, Kpad, ldC, ldAdd);
    };
    auto cblk = [](int n) { return (n + 255) / 256; };

    // ---- prep ----
    prep_idx<<<cblk(MB), 256, 0, stream>>>(prem, hyp, idx_p, idx_h);
    conv_w <<<cblk(G3 * 320), 256, 0, stream>>>(p_Wih, pWih_b, G3, EMBD, 320, EMBD, 0);
    conv_w <<<cblk(G3 * 320), 256, 0, stream>>>(h_Wih, hWih_b, G3, EMBD, 320, EMBD, 0);
    conv_w <<<cblk(G3 * ND), 256, 0, stream>>>(p_Whh, pWhh_b, G3, ND, ND, ND, 0);
    conv_w <<<cblk(G3 * ND), 256, 0, stream>>>(h_Whh, hWhh_b, G3, ND, ND, ND, 0);
    conv_w <<<cblk(G3 * ND), 256, 0, stream>>>(m_Wih, mWihL, G3, ND, ND, 2 * ND, 0);
    conv_w <<<cblk(G3 * ND), 256, 0, stream>>>(m_Wih, mWihR, G3, ND, ND, 2 * ND, ND);
    conv_w <<<cblk(G3 * ND), 256, 0, stream>>>(m_Whh, Wcat + (size_t)ND * ND, G3, ND, ND, ND, 0);
    conv_wT<<<cblk(ND * ND), 256, 0, stream>>>(W_y, WyT_b, ND, ND, ND, ND);
    conv_wT<<<cblk(ND * ND), 256, 0, stream>>>(W_h, WhT_b, ND, ND, ND, ND);
    conv_wT<<<cblk(ND * ND), 256, 0, stream>>>(W_r, Wcat, ND, ND, ND, ND);
    make_bias_cat<<<cblk(2048), 256, 0, stream>>>(m_bhh, bias_cat);
    zero_kernel<<<cblk(B_SZ * ND), 256, 0, stream>>>(h, B_SZ * ND);
    zero_kernel<<<cblk(B_SZ * ND), 256, 0, stream>>>(r_, B_SZ * ND);

    // ---- premise GRU ----
    gemm(E, idx_p, pWih_b, p_bih, nullptr, GI, MB, G3, EMBD, EMBD, 320, G3, 0);
    for (int t = 0; t < T_SZ; ++t) {
        gemm(h, nullptr, pWhh_b, p_bhh, nullptr, ghb, B_SZ, G3, ND, ND, ND, G3, 0);
        const float* oprev = (t == 0) ? o_p : o_p + (size_t)(t - 1) * B_SZ * ND;
        gru_combine<<<cblk(B_SZ * ND), 256, 0, stream>>>(
            GI + (size_t)t * B_SZ * G3, G3, ghb, G3, h, oprev,
            o_p + (size_t)t * B_SZ * ND, prem, t, t == 0 ? 1 : 0);
    }

    // ---- hypothesis GRU ----
    gemm(E, idx_h, hWih_b, h_bih, nullptr, GI, MB, G3, EMBD, EMBD, 320, G3, 0);
    for (int t = 0; t < T_SZ; ++t) {
        gemm(h, nullptr, hWhh_b, h_bhh, nullptr, ghb, B_SZ, G3, ND, ND, ND, G3, 0);
        const float* oprev = (t == 0) ? o_h : o_h + (size_t)(t - 1) * B_SZ * ND;
        gru_combine<<<cblk(B_SZ * ND), 256, 0, stream>>>(
            GI + (size_t)t * B_SZ * G3, G3, ghb, G3, h, oprev,
            o_h + (size_t)t * B_SZ * ND, hyp, t, t == 0 ? 1 : 0);
    }

    // ---- attention precompute ----
    gemm(o_p, nullptr, WyT_b, nullptr, nullptr, Yw, MB, ND, ND, ND, ND, ND, 0);
    gemm(o_h, nullptr, WhT_b, nullptr, nullptr, OHWh, MB, ND, ND, ND, ND, ND, 0);
    gemm(o_h, nullptr, mWihR, m_bih, nullptr, GI, MB, G3, ND, ND, ND, G3, 0);  // OH_GI

    // ---- match loop ----
    for (int t = 0; t < T_SZ; ++t) {
        // [s | gh] = r @ [W_r | m_Whh^T] + [0 | m_bhh]
        gemm(r_, nullptr, Wcat, bias_cat, nullptr, scat, B_SZ, 2048, ND, ND, ND, 2048, 0);
        alpha_logits<<<(B_SZ * T_SZ * 64) / 256, 256, 0, stream>>>(
            Yw, scat, 2048, OHWh + (size_t)t * B_SZ * ND, W_alpha, prem, alphaBuf);
        attn_apply<<<B_SZ, 256, 0, stream>>>(alphaBuf, o_p, abuf);
        // gi = a @ m_Wih_L^T + OH_GI[t] (has m_bih)
        gemm(abuf, nullptr, mWihL, nullptr, GI + (size_t)t * B_SZ * G3, gib,
             B_SZ, G3, ND, ND, ND, G3, G3);
        gru_combine<<<cblk(B_SZ * ND), 256, 0, stream>>>(
            gib, G3, scat + ND, 2048, r_, nullptr, nullptr, hyp, t, 0);
    }

    final_logits<<<B_SZ, 64, 0, stream>>>(r_, out_W, out_b, out);
}